// Round 1
// baseline (65859.827 us; speedup 1.0000x reference)
//
#include <hip/hip_runtime.h>
#include <cstdint>
#include <cstddef>

// Problem constants (match reference)
#define N_ITEMS 16384
#define D_STATE 2048
#define D_SEM   1024
#define S_SLOTS 4096
#define DTHRESH 2.0f

// Scan-kernel machine config: 512 WGs x 256 thr, 8 slots/WG.
// LDS/WG ~37 KB -> >=4 blocks/CU capacity; 512 blocks <= 256 CUs * 2 needed,
// so all WGs are co-resident under a normal launch (persistent kernel).
#define NWG 512
#define SPW 8
#define TPB 256

#define SCOPE __HIP_MEMORY_SCOPE_AGENT
typedef unsigned long long u64;
typedef unsigned int u32;

// ---------------------------------------------------------------------------
// GEMM: content[i,j] = sum_d states[i,d]*W[j,d] + b[j]
// 64x64 tile, BK=16, 4x4 per-thread micro-tile, fp32 (no fp32 MFMA on CDNA4).
// ---------------------------------------------------------------------------
#define TM 64
#define TN 64
#define TK 16

__global__ __launch_bounds__(256)
void gemm_kernel(const float* __restrict__ A, const float* __restrict__ W,
                 const float* __restrict__ bias, float* __restrict__ C) {
  __shared__ float As[TK][TM + 4];
  __shared__ float Bs[TK][TN + 4];
  const int t = threadIdx.x;
  const int ty = t >> 4, tx = t & 15;
  const int i0 = blockIdx.x * TM, j0 = blockIdx.y * TN;
  const int lrow = t >> 2;
  const int lcol = (t & 3) << 2;
  float acc[4][4] = {{0.f, 0.f, 0.f, 0.f}};
  const float* ap = A + (size_t)(i0 + lrow) * D_STATE + lcol;
  const float* wp = W + (size_t)(j0 + lrow) * D_STATE + lcol;
  for (int k0 = 0; k0 < D_STATE; k0 += TK) {
    float4 av = *(const float4*)(ap + k0);
    float4 wv = *(const float4*)(wp + k0);
    __syncthreads();
    As[lcol + 0][lrow] = av.x; As[lcol + 1][lrow] = av.y;
    As[lcol + 2][lrow] = av.z; As[lcol + 3][lrow] = av.w;
    Bs[lcol + 0][lrow] = wv.x; Bs[lcol + 1][lrow] = wv.y;
    Bs[lcol + 2][lrow] = wv.z; Bs[lcol + 3][lrow] = wv.w;
    __syncthreads();
#pragma unroll
    for (int kk = 0; kk < TK; kk++) {
      const float a0 = As[kk][ty * 4 + 0], a1 = As[kk][ty * 4 + 1];
      const float a2 = As[kk][ty * 4 + 2], a3 = As[kk][ty * 4 + 3];
      const float b0 = Bs[kk][tx * 4 + 0], b1 = Bs[kk][tx * 4 + 1];
      const float b2 = Bs[kk][tx * 4 + 2], b3 = Bs[kk][tx * 4 + 3];
      acc[0][0] = fmaf(a0, b0, acc[0][0]); acc[0][1] = fmaf(a0, b1, acc[0][1]);
      acc[0][2] = fmaf(a0, b2, acc[0][2]); acc[0][3] = fmaf(a0, b3, acc[0][3]);
      acc[1][0] = fmaf(a1, b0, acc[1][0]); acc[1][1] = fmaf(a1, b1, acc[1][1]);
      acc[1][2] = fmaf(a1, b2, acc[1][2]); acc[1][3] = fmaf(a1, b3, acc[1][3]);
      acc[2][0] = fmaf(a2, b0, acc[2][0]); acc[2][1] = fmaf(a2, b1, acc[2][1]);
      acc[2][2] = fmaf(a2, b2, acc[2][2]); acc[2][3] = fmaf(a2, b3, acc[2][3]);
      acc[3][0] = fmaf(a3, b0, acc[3][0]); acc[3][1] = fmaf(a3, b1, acc[3][1]);
      acc[3][2] = fmaf(a3, b2, acc[3][2]); acc[3][3] = fmaf(a3, b3, acc[3][3]);
    }
  }
#pragma unroll
  for (int yi = 0; yi < 4; yi++) {
#pragma unroll
    for (int xi = 0; xi < 4; xi++) {
      const int col = j0 + tx * 4 + xi;
      C[(size_t)(i0 + ty * 4 + yi) * D_SEM + col] = acc[yi][xi] + bias[col];
    }
  }
}

// ---------------------------------------------------------------------------
// Sequential consolidation scan. 512 persistent WGs; traces live in LDS
// (8 rows x 4KB per WG). Per step: local 8-slot argmin -> publish packed
// (dist|slot|tag) word -> WG0 global argmin + branch decision -> fan-out to
// per-WG mailboxes -> owner applies. Data rides inside the tagged atomic
// word, so relaxed device-scope atomics suffice.
// ---------------------------------------------------------------------------
__device__ inline u64 poll_word(u64* addr, u32 tag, int* ok) {
  long cnt = 0;
  for (;;) {
    u64 v = __hip_atomic_load(addr, __ATOMIC_RELAXED, SCOPE);
    if ((u32)(v & 0xFFFFULL) == tag) return v;
    if (++cnt > 1000000000L) { *ok = 0; return v; }  // deadlock guard: fail, don't hang
  }
}

__global__ __launch_bounds__(256)
void scan_kernel(const float* __restrict__ content,
                 const float* __restrict__ rewards,
                 const float* __restrict__ traces0,
                 const float* __restrict__ strengths0,
                 float* __restrict__ out,
                 u64* __restrict__ partials,
                 u64* __restrict__ decs,
                 float* __restrict__ strengths_g) {
  __shared__ float tr[SPW][D_SEM];       // 32 KB: this WG's trace rows
  __shared__ float cbuf[D_SEM];          // 4 KB: current content row
  __shared__ float dist_l[SPW];
  __shared__ u64 redbuf[4];
  __shared__ u64 bc_dec;
  __shared__ float rsum[4];
  __shared__ int sh_num, sh_ptr, sh_abort;

  const int w = blockIdx.x;
  const int t = threadIdx.x;
  const int lane = t & 63;
  const int wave = t >> 6;
  const int slot0 = w * SPW;

  // init: load my trace rows (general: reference may pass nonzero traces)
  for (int s = 0; s < SPW; s++) {
    float4 v = *(const float4*)(traces0 + (size_t)(slot0 + s) * D_SEM + (t << 2));
    *(float4*)&tr[s][t << 2] = v;
  }
  if (w == 0) {
    for (int s = t; s < S_SLOTS; s += TPB) strengths_g[s] = strengths0[s];
  }
  if (t == 0) { sh_num = 0; sh_ptr = 0; sh_abort = 0; }
  { // stage content row 0
    float4 v = *(const float4*)(content + (t << 2));
    *(float4*)&cbuf[t << 2] = v;
  }
  __syncthreads();

  for (int i = 0; i < N_ITEMS; i++) {
    const u32 tag = (u32)((i + 1) & 0xFFFF);
    // prefetch next content row into registers (latency hidden by sync chain)
    float4 cnext;
    if (i + 1 < N_ITEMS)
      cnext = *(const float4*)(content + (size_t)(i + 1) * D_SEM + (t << 2));
    float rw = 0.f;
    if (w == 0 && t == 0) rw = rewards[i];  // issued early, used at decide

    // distances: wave v handles slots v, v+4; lane covers dims 4*lane + 256*j
    for (int s = wave; s < SPW; s += 4) {
      float acc = 0.f;
#pragma unroll
      for (int j = 0; j < 4; j++) {
        const float4 tv = *(const float4*)&tr[s][(lane << 2) + (j << 8)];
        const float4 cv = *(const float4*)&cbuf[(lane << 2) + (j << 8)];
        float d;
        d = tv.x - cv.x; acc = fmaf(d, d, acc);
        d = tv.y - cv.y; acc = fmaf(d, d, acc);
        d = tv.z - cv.z; acc = fmaf(d, d, acc);
        d = tv.w - cv.w; acc = fmaf(d, d, acc);
      }
#pragma unroll
      for (int o = 32; o; o >>= 1) acc += __shfl_down(acc, o, 64);
      if (lane == 0) dist_l[s] = sqrtf(acc);
    }
    __syncthreads();

    // t0: local argmin over valid slots, publish
    if (t == 0) {
      const int numc = sh_num;
      float best = __builtin_huge_valf();
      int bslot = slot0;
      for (int s = 0; s < SPW; s++) {
        if (slot0 + s < numc) {
          const float d = dist_l[s];
          if (d < best) { best = d; bslot = slot0 + s; }
        }
      }
      const u64 pw = ((u64)__float_as_uint(best) << 32) |
                     ((u64)(u32)bslot << 16) | (u64)tag;
      __hip_atomic_store(&partials[w], pw, __ATOMIC_RELAXED, SCOPE);
    }

    if (w == 0) {
      // master: gather 512 partials (2 per thread), lexicographic min (dist,slot)
      int ok = 1;
      u64 v1 = poll_word(&partials[t], tag, &ok);
      u64 v2 = poll_word(&partials[t + 256], tag, &ok);
      if (!ok) sh_abort = 1;
      u64 k1 = v1 >> 16, k2 = v2 >> 16;
      u64 k = k1 < k2 ? k1 : k2;
#pragma unroll
      for (int o = 32; o; o >>= 1) {
        u64 other = __shfl_down(k, o, 64);
        if (other < k) k = other;
      }
      if (lane == 0) redbuf[wave] = k;
      __syncthreads();
      if (t == 0) {
        u64 kk = redbuf[0];
        if (redbuf[1] < kk) kk = redbuf[1];
        if (redbuf[2] < kk) kk = redbuf[2];
        if (redbuf[3] < kk) kk = redbuf[3];
        const float ndist = __uint_as_float((u32)(kk >> 16));
        const int nslot = (int)(kk & 0xFFFFULL);
        const int numc = sh_num, ptrc = sh_ptr;
        const bool upd = (numc > 0) && (ndist < DTHRESH);
        // eff_lr = LR*(1+|r|), separate fp32 ops to match reference rounding
        const float efflr = __fmul_rn(0.01f, __fadd_rn(1.0f, fabsf(rw)));
        const int slot = upd ? nslot : ptrc;
        bc_dec = ((u64)__float_as_uint(efflr) << 32) |
                 ((u64)(u32)((slot & 0xFFF) | (upd ? 0x8000 : 0)) << 16) |
                 (u64)tag;
      }
      __syncthreads();
      const u64 dw = bc_dec;
      __hip_atomic_store(&decs[t], dw, __ATOMIC_RELAXED, SCOPE);
      __hip_atomic_store(&decs[t + 256], dw, __ATOMIC_RELAXED, SCOPE);
    } else {
      if (t == 0) {
        int ok = 1;
        u64 v = poll_word(&decs[w], tag, &ok);
        if (!ok) sh_abort = 1;
        bc_dec = v;
      }
      __syncthreads();
    }

    if (sh_abort) break;  // residency failure: bail (wrong answer, no hang)

    // decode + apply
    const u64 dec = bc_dec;
    const int slot = (int)((dec >> 16) & 0xFFFULL);
    const bool upd = ((dec >> 16) & 0x8000ULL) != 0;
    const float efflr = __uint_as_float((u32)(dec >> 32));
    if ((slot >> 3) == w) {  // owner WG mutates its LDS row
      const int s = slot & 7;
#pragma unroll
      for (int j = 0; j < 4; j++) {
        const int dd = (t << 2) + j;
        const float c = cbuf[dd];
        const float tv = tr[s][dd];
        // reference: delta=c-t; t += delta*lr  (separate rounds, no fma)
        tr[s][dd] = upd ? __fadd_rn(tv, __fmul_rn(__fsub_rn(c, tv), efflr)) : c;
      }
    }
    if (t == 0) {
      if (!upd) {
        sh_ptr = (sh_ptr + 1) & (S_SLOTS - 1);
        sh_num = min(sh_num + 1, S_SLOTS);
      }
    }
    if (w == 0 && t == 0) {  // master-private strengths (off critical path)
      if (upd) strengths_g[slot] += 1.0f; else strengths_g[slot] = 1.0f;
    }
    __syncthreads();
    if (i + 1 < N_ITEMS) *(float4*)&cbuf[t << 2] = cnext;
    __syncthreads();
  }

  // epilogue: traces
  for (int s = 0; s < SPW; s++) {
    float4 v = *(const float4*)&tr[s][t << 2];
    *(float4*)(out + (size_t)(slot0 + s) * D_SEM + (t << 2)) = v;
  }
  if (w == 0) {
    float* outs = out + (size_t)S_SLOTS * D_SEM;
    const int numc = sh_num;
    float lsum = 0.f;
    for (int s = t; s < S_SLOTS; s += TPB) {
      const float sv = strengths_g[s];
      outs[s] = sv;
      if (s < numc) lsum += sv;
    }
#pragma unroll
    for (int o = 32; o; o >>= 1) lsum += __shfl_down(lsum, o, 64);
    if (lane == 0) rsum[wave] = lsum;
    __syncthreads();
    if (t == 0) {
      const float total = rsum[0] + rsum[1] + rsum[2] + rsum[3];
      const int valid = numc < S_SLOTS ? numc : S_SLOTS;
      float denom = (float)valid;
      if (denom < 1.f) denom = 1.f;
      outs[S_SLOTS + 0] = (float)numc;
      outs[S_SLOTS + 1] = (float)N_ITEMS;
      outs[S_SLOTS + 2] = (numc > 0) ? (total / denom) : 0.f;
    }
  }
}

// ---------------------------------------------------------------------------
extern "C" void kernel_launch(void* const* d_in, const int* in_sizes, int n_in,
                              void* d_out, int out_size, void* d_ws, size_t ws_size,
                              hipStream_t stream) {
  const float* states  = (const float*)d_in[0];
  const float* rewards = (const float*)d_in[1];
  const float* W       = (const float*)d_in[2];
  const float* bias    = (const float*)d_in[3];
  const float* traces0 = (const float*)d_in[4];
  const float* str0    = (const float*)d_in[5];
  float* out = (float*)d_out;

  // workspace layout: content (64 MB) | partials (4 KB) | decs (4 KB) | strengths (16 KB)
  float* content = (float*)d_ws;
  u64* partials  = (u64*)((char*)d_ws + (size_t)N_ITEMS * D_SEM * sizeof(float));
  u64* decs      = partials + NWG;
  float* strengths_g = (float*)(decs + NWG);

  dim3 g1(N_ITEMS / TM, D_SEM / TN);
  gemm_kernel<<<g1, 256, 0, stream>>>(states, W, bias, content);
  scan_kernel<<<NWG, TPB, 0, stream>>>(content, rewards, traces0, str0, out,
                                       partials, decs, strengths_g);
}

// Round 2
// 36768.683 us; speedup vs baseline: 1.7912x; 1.7912x over previous
//
#include <hip/hip_runtime.h>
#include <cstdint>
#include <cstddef>

// Problem constants (match reference)
#define N_ITEMS 16384
#define D_STATE 2048
#define D_SEM   1024
#define S_SLOTS 4096
#define DTHRESH 2.0f

#define B_ITEMS 256              // sequential-scan block size
#define NBLK    (N_ITEMS / B_ITEMS)   // 64
#define CHUNK_BLKS 16            // content-GEMM chunking (16 MB buffer)
#define CHUNK_ITEMS (B_ITEMS * CHUNK_BLKS)  // 4096

typedef unsigned long long u64;
typedef unsigned int u32;

// ---------------------------------------------------------------------------
// Content GEMM: C[i,j] = sum_d A[i,d]*W[j,d] + b[j].  64x64 tile, K=2048.
// ---------------------------------------------------------------------------
__global__ __launch_bounds__(256)
void gemm_kernel(const float* __restrict__ A, const float* __restrict__ W,
                 const float* __restrict__ bias, float* __restrict__ C) {
  __shared__ float As[16][68];
  __shared__ float Bs[16][68];
  const int t = threadIdx.x;
  const int ty = t >> 4, tx = t & 15;
  const int i0 = blockIdx.x * 64, j0 = blockIdx.y * 64;
  const int lrow = t >> 2, lcol = (t & 3) << 2;
  float acc[4][4] = {{0.f}};
  const float* ap = A + (size_t)(i0 + lrow) * D_STATE + lcol;
  const float* wp = W + (size_t)(j0 + lrow) * D_STATE + lcol;
  for (int k0 = 0; k0 < D_STATE; k0 += 16) {
    float4 av = *(const float4*)(ap + k0);
    float4 wv = *(const float4*)(wp + k0);
    __syncthreads();
    As[lcol + 0][lrow] = av.x; As[lcol + 1][lrow] = av.y;
    As[lcol + 2][lrow] = av.z; As[lcol + 3][lrow] = av.w;
    Bs[lcol + 0][lrow] = wv.x; Bs[lcol + 1][lrow] = wv.y;
    Bs[lcol + 2][lrow] = wv.z; Bs[lcol + 3][lrow] = wv.w;
    __syncthreads();
#pragma unroll
    for (int kk = 0; kk < 16; kk++) {
      float a[4], b[4];
#pragma unroll
      for (int y = 0; y < 4; y++) a[y] = As[kk][ty * 4 + y];
#pragma unroll
      for (int x = 0; x < 4; x++) b[x] = Bs[kk][tx * 4 + x];
#pragma unroll
      for (int y = 0; y < 4; y++)
#pragma unroll
        for (int x = 0; x < 4; x++) acc[y][x] = fmaf(a[y], b[x], acc[y][x]);
    }
  }
#pragma unroll
  for (int y = 0; y < 4; y++)
#pragma unroll
    for (int x = 0; x < 4; x++) {
      const int col = j0 + tx * 4 + x;
      C[(size_t)(i0 + ty * 4 + y) * D_SEM + col] = acc[y][x] + bias[col];
    }
}

// ---------------------------------------------------------------------------
// Per-chunk block-diagonal Gram: G[z][i][j] = c_i . c_j within block z.
// grid (4,4,CHUNK_BLKS), 64x64 tiles, K=1024.
// ---------------------------------------------------------------------------
__global__ __launch_bounds__(256)
void gram_kernel(const float* __restrict__ Cc, float* __restrict__ G) {
  const int z = blockIdx.z;
  const float* A = Cc + (size_t)z * B_ITEMS * D_SEM;
  __shared__ float As[16][68];
  __shared__ float Bs[16][68];
  const int t = threadIdx.x;
  const int ty = t >> 4, tx = t & 15;
  const int i0 = blockIdx.x * 64, j0 = blockIdx.y * 64;
  const int lrow = t >> 2, lcol = (t & 3) << 2;
  float acc[4][4] = {{0.f}};
  const float* ap = A + (size_t)(i0 + lrow) * D_SEM + lcol;
  const float* wp = A + (size_t)(j0 + lrow) * D_SEM + lcol;
  for (int k0 = 0; k0 < D_SEM; k0 += 16) {
    float4 av = *(const float4*)(ap + k0);
    float4 wv = *(const float4*)(wp + k0);
    __syncthreads();
    As[lcol + 0][lrow] = av.x; As[lcol + 1][lrow] = av.y;
    As[lcol + 2][lrow] = av.z; As[lcol + 3][lrow] = av.w;
    Bs[lcol + 0][lrow] = wv.x; Bs[lcol + 1][lrow] = wv.y;
    Bs[lcol + 2][lrow] = wv.z; Bs[lcol + 3][lrow] = wv.w;
    __syncthreads();
#pragma unroll
    for (int kk = 0; kk < 16; kk++) {
      float a[4], b[4];
#pragma unroll
      for (int y = 0; y < 4; y++) a[y] = As[kk][ty * 4 + y];
#pragma unroll
      for (int x = 0; x < 4; x++) b[x] = Bs[kk][tx * 4 + x];
#pragma unroll
      for (int y = 0; y < 4; y++)
#pragma unroll
        for (int x = 0; x < 4; x++) acc[y][x] = fmaf(a[y], b[x], acc[y][x]);
    }
  }
  float* Gz = G + (size_t)z * B_ITEMS * B_ITEMS;
#pragma unroll
  for (int y = 0; y < 4; y++)
#pragma unroll
    for (int x = 0; x < 4; x++)
      Gz[(size_t)(i0 + ty * 4 + y) * B_ITEMS + j0 + tx * 4 + x] = acc[y][x];
}

// ---------------------------------------------------------------------------
// Per-block pre-distance: Q[i][s] = ||t_s||^2 - 2 * c_i . t_s  (s < limit).
// d^2(c_i,t_s) = Q[i][s] + ||c_i||^2.  grid (4,64); slot-tiles past the
// max-possible-valid limit exit early (their Q is never read).
// ---------------------------------------------------------------------------
__global__ __launch_bounds__(256)
void pgemm_kernel(const float* __restrict__ A,   // content block 256 x 1024
                  const float* __restrict__ T,   // traces (= out) 4096 x 1024
                  const float* __restrict__ n_g, // ||t_s||^2
                  float* __restrict__ Q,
                  const int* __restrict__ state) {
  const int limit = min(state[0] + B_ITEMS, S_SLOTS);
  const int j0 = blockIdx.y * 64;
  if (j0 >= limit) return;
  __shared__ float As[16][68];
  __shared__ float Bs[16][68];
  const int t = threadIdx.x;
  const int ty = t >> 4, tx = t & 15;
  const int i0 = blockIdx.x * 64;
  const int lrow = t >> 2, lcol = (t & 3) << 2;
  float acc[4][4] = {{0.f}};
  const float* ap = A + (size_t)(i0 + lrow) * D_SEM + lcol;
  const float* wp = T + (size_t)(j0 + lrow) * D_SEM + lcol;
  for (int k0 = 0; k0 < D_SEM; k0 += 16) {
    float4 av = *(const float4*)(ap + k0);
    float4 wv = *(const float4*)(wp + k0);
    __syncthreads();
    As[lcol + 0][lrow] = av.x; As[lcol + 1][lrow] = av.y;
    As[lcol + 2][lrow] = av.z; As[lcol + 3][lrow] = av.w;
    Bs[lcol + 0][lrow] = wv.x; Bs[lcol + 1][lrow] = wv.y;
    Bs[lcol + 2][lrow] = wv.z; Bs[lcol + 3][lrow] = wv.w;
    __syncthreads();
#pragma unroll
    for (int kk = 0; kk < 16; kk++) {
      float a[4], b[4];
#pragma unroll
      for (int y = 0; y < 4; y++) a[y] = As[kk][ty * 4 + y];
#pragma unroll
      for (int x = 0; x < 4; x++) b[x] = Bs[kk][tx * 4 + x];
#pragma unroll
      for (int y = 0; y < 4; y++)
#pragma unroll
        for (int x = 0; x < 4; x++) acc[y][x] = fmaf(a[y], b[x], acc[y][x]);
    }
  }
#pragma unroll
  for (int y = 0; y < 4; y++)
#pragma unroll
    for (int x = 0; x < 4; x++) {
      const int col = j0 + tx * 4 + x;
      Q[(size_t)(i0 + ty * 4 + y) * S_SLOTS + col] = n_g[col] - 2.0f * acc[y][x];
    }
}

// ---------------------------------------------------------------------------
// init: copy traces0 -> out (working traces), n_g[s] = ||t_s||^2, reset state.
// ---------------------------------------------------------------------------
__global__ __launch_bounds__(256)
void init_kernel(const float* __restrict__ traces0, float* __restrict__ out,
                 float* __restrict__ n_g, int* __restrict__ state) {
  __shared__ float wsum[4];
  const int s = blockIdx.x, t = threadIdx.x;
  const int lane = t & 63, wave = t >> 6;
  float4 v = *(const float4*)(traces0 + (size_t)s * D_SEM + 4 * t);
  *(float4*)(out + (size_t)s * D_SEM + 4 * t) = v;
  float nn = v.x * v.x + v.y * v.y + v.z * v.z + v.w * v.w;
#pragma unroll
  for (int o = 32; o; o >>= 1) nn += __shfl_down(nn, o, 64);
  if (lane == 0) wsum[wave] = nn;
  __syncthreads();
  if (t == 0) n_g[s] = wsum[0] + wsum[1] + wsum[2] + wsum[3];
  if (s == 0 && t == 0) { state[0] = 0; state[1] = 0; }
}

// ---------------------------------------------------------------------------
// Sequential scan over one block of 256 items. SINGLE workgroup, 512 thr.
// Thread t holds Q-row slice for slots 8t..8t+7 in registers (prefetched).
// Per step: d2 = Q + g_i -> packed u64 argmin -> decision -> rank-1 scalar
// update of future rows (register fixup for row i+1, L2 RMW for rows > i+1).
// ---------------------------------------------------------------------------
__global__ __launch_bounds__(512)
void scan_kernel(float* __restrict__ Q, const float* __restrict__ Gb,
                 const float* __restrict__ rewards, const float* __restrict__ n_g,
                 int* __restrict__ state, u64* __restrict__ decs) {
  __shared__ float n_l[S_SLOTS];     // ||t_s||^2, tracked incrementally
  __shared__ float rew[B_ITEMS];
  __shared__ float gdiag[B_ITEMS];   // ||c_i||^2
  __shared__ u64 partials[8];
  __shared__ u32 pub_slotupd;        // slot | upd<<31
  __shared__ float pub_lr, pub_nold, pub_nnew;
  __shared__ int sh_num[2], sh_ptr[2];
  __shared__ u32 dslot[B_ITEMS];
  __shared__ float dlr[B_ITEMS];

  const int t = threadIdx.x;          // 0..511
  const int lane = t & 63, wave = t >> 6;

  for (int s = t; s < S_SLOTS; s += 512) n_l[s] = n_g[s];
  if (t < B_ITEMS) {
    rew[t] = rewards[t];
    gdiag[t] = Gb[(size_t)t * B_ITEMS + t];
  }
  if (t == 0) { sh_num[0] = state[0]; sh_ptr[0] = state[1]; }
  // prefetch Q row 0 (slots 8t..8t+7)
  float4 n0 = *(const float4*)(Q + 8 * t);
  float4 n1 = *(const float4*)(Q + 8 * t + 4);
  __syncthreads();

  int par = 0;
  for (int i = 0; i < B_ITEMS; i++) {
    float4 c0 = n0, c1 = n1;
    if (i + 1 < B_ITEMS) {   // prefetch next row (stale only wrt this step)
      n0 = *(const float4*)(Q + (size_t)(i + 1) * S_SLOTS + 8 * t);
      n1 = *(const float4*)(Q + (size_t)(i + 1) * S_SLOTS + 8 * t + 4);
    }
    const int num = sh_num[par];
    const float gi = gdiag[i];
    const int s0 = 8 * t;
    u64 best = ~0ull;
#define KEYC(comp, idx) { const int ss = s0 + idx; \
    if (ss < num) { const float d2 = fmaxf(comp + gi, 0.f); \
      const u64 key = ((u64)__float_as_uint(d2) << 32) | (u32)ss; \
      if (key < best) best = key; } }
    KEYC(c0.x, 0) KEYC(c0.y, 1) KEYC(c0.z, 2) KEYC(c0.w, 3)
    KEYC(c1.x, 4) KEYC(c1.y, 5) KEYC(c1.z, 6) KEYC(c1.w, 7)
#undef KEYC
#pragma unroll
    for (int o = 32; o; o >>= 1) {
      const u64 v = __shfl_down(best, o, 64);
      if (v < best) best = v;
    }
    if (lane == 0) partials[wave] = best;
    __syncthreads();

    if (t == 0) {  // phase B: decision (others idle at barrier; LDS safe)
      u64 bk = partials[0];
#pragma unroll
      for (int wv = 1; wv < 8; wv++) if (partials[wv] < bk) bk = partials[wv];
      const float d2b = __uint_as_float((u32)(bk >> 32));
      const int nslot = (int)(u32)bk;
      const int numc = sh_num[par], ptrc = sh_ptr[par];
      const bool upd = (numc > 0) && (sqrtf(d2b) < DTHRESH);
      const float lr = __fmul_rn(0.01f, __fadd_rn(1.0f, fabsf(rew[i])));
      const int slot = upd ? nslot : ptrc;
      const float n_old = n_l[slot];
      float n_new;
      if (upd) {
        const float omr = 1.0f - lr;
        const float pcur = 0.5f * (n_old + gi - d2b);
        n_new = omr * omr * n_old + 2.0f * lr * omr * pcur + lr * lr * gi;
        sh_num[par ^ 1] = numc; sh_ptr[par ^ 1] = ptrc;
      } else {
        n_new = gi;
        sh_num[par ^ 1] = min(numc + 1, S_SLOTS);
        sh_ptr[par ^ 1] = (ptrc + 1) & (S_SLOTS - 1);
      }
      n_l[slot] = n_new;
      dslot[i] = (u32)slot | (upd ? 0x80000000u : 0u);
      dlr[i] = lr;
      pub_slotupd = (u32)slot | (upd ? 0x80000000u : 0u);
      pub_lr = lr; pub_nold = n_old; pub_nnew = n_new;
    }
    __syncthreads();

    // phase C: apply mutation to future rows
    const u32 su = pub_slotupd;
    const int slot = (int)(su & 0x7FFFFFFFu);
    const bool upd = (su & 0x80000000u) != 0;
    const float lr = pub_lr, n_old = pub_nold, n_new = pub_nnew;
    const float omr = 1.0f - lr;
    if (i + 1 < B_ITEMS && t == (slot >> 3)) {  // register fixup, row i+1
      const float gnext = Gb[(size_t)i * B_ITEMS + (i + 1)];
      const int k = slot & 7;
      float q_old = k == 0 ? n0.x : k == 1 ? n0.y : k == 2 ? n0.z : k == 3 ? n0.w
                  : k == 4 ? n1.x : k == 5 ? n1.y : k == 6 ? n1.z : n1.w;
      const float p_old = 0.5f * (n_old - q_old);
      const float p_new = upd ? (omr * p_old + lr * gnext) : gnext;
      const float q_new = n_new - 2.0f * p_new;
      switch (k) {
        case 0: n0.x = q_new; break; case 1: n0.y = q_new; break;
        case 2: n0.z = q_new; break; case 3: n0.w = q_new; break;
        case 4: n1.x = q_new; break; case 5: n1.y = q_new; break;
        case 6: n1.z = q_new; break; default: n1.w = q_new; break;
      }
    }
    if (t > i + 1 && t < B_ITEMS) {  // L2 RMW for rows i+2..255
      const float gv = Gb[(size_t)i * B_ITEMS + t];
      float* qp = Q + (size_t)t * S_SLOTS + slot;
      float p_new;
      if (upd) {
        const float p_old = 0.5f * (n_old - *qp);
        p_new = omr * p_old + lr * gv;
      } else {
        p_new = gv;
      }
      *qp = n_new - 2.0f * p_new;
    }
    par ^= 1;
    __syncthreads();  // drains RMW stores + prefetch before next step
  }

  if (t == 0) { state[0] = sh_num[par]; state[1] = sh_ptr[par]; }
  if (t < B_ITEMS)
    decs[t] = ((u64)__float_as_uint(dlr[t]) << 32) | (u64)dslot[t];
}

// ---------------------------------------------------------------------------
// apply: materialize the block's trace mutations. WG j owns slot_j iff step j
// is the LAST step touching it. Composition: t = alpha*t_snap + sum beta_j c_j.
// Recomputes exact ||t||^2 -> n_g (bounds numeric drift to one block).
// ---------------------------------------------------------------------------
__global__ __launch_bounds__(256)
void apply_kernel(const float* __restrict__ content,  // block 256 x 1024
                  const u64* __restrict__ decs,       // 256 decisions
                  float* __restrict__ traces,         // = out
                  float* __restrict__ n_g) {
  __shared__ u32 aslot[B_ITEMS];
  __shared__ float alr[B_ITEMS];
  __shared__ float betas[B_ITEMS];
  __shared__ int notowner;
  __shared__ float wsum[4];
  const int t = threadIdx.x, j = blockIdx.x;
  const int lane = t & 63, wave = t >> 6;
  const u64 d = decs[t];
  aslot[t] = (u32)(d & 0xFFFFFFFFull);
  alr[t] = __uint_as_float((u32)(d >> 32));
  if (t == 0) notowner = 0;
  __syncthreads();
  const u32 myslot = aslot[j] & 0x7FFFFFFFu;
  if (t > j && (aslot[t] & 0x7FFFFFFFu) == myslot) notowner = 1;
  __syncthreads();
  if (notowner) return;

  float alpha = 1.f, beta = 0.f;
  for (int k = 0; k < B_ITEMS; k++) {
    const u32 a = aslot[k];
    if ((a & 0x7FFFFFFFu) == myslot) {
      const float lr = alr[k];
      if (a & 0x80000000u) {           // update
        const float om = 1.f - lr;
        alpha *= om; beta *= om;
        if (t == k) beta += lr;
      } else {                         // insert
        alpha = 0.f; beta = (t == k) ? 1.f : 0.f;
      }
    }
  }
  betas[t] = beta;
  __syncthreads();

  float4 v = *(const float4*)(traces + (size_t)myslot * D_SEM + 4 * t);
  v.x *= alpha; v.y *= alpha; v.z *= alpha; v.w *= alpha;
  for (int k = 0; k < B_ITEMS; k++) {
    if ((aslot[k] & 0x7FFFFFFFu) == myslot) {
      const float bk = betas[k];
      const float4 c = *(const float4*)(content + (size_t)k * D_SEM + 4 * t);
      v.x = fmaf(bk, c.x, v.x); v.y = fmaf(bk, c.y, v.y);
      v.z = fmaf(bk, c.z, v.z); v.w = fmaf(bk, c.w, v.w);
    }
  }
  *(float4*)(traces + (size_t)myslot * D_SEM + 4 * t) = v;
  float nn = v.x * v.x + v.y * v.y + v.z * v.z + v.w * v.w;
#pragma unroll
  for (int o = 32; o; o >>= 1) nn += __shfl_down(nn, o, 64);
  if (lane == 0) wsum[wave] = nn;
  __syncthreads();
  if (t == 0) n_g[myslot] = wsum[0] + wsum[1] + wsum[2] + wsum[3];
}

// ---------------------------------------------------------------------------
// finalize: replay decision log for strengths; write strengths + scalars.
// ---------------------------------------------------------------------------
__global__ __launch_bounds__(256)
void finalize_kernel(const float* __restrict__ strengths0,
                     const u64* __restrict__ decs,
                     const int* __restrict__ state, float* __restrict__ out) {
  __shared__ float str[S_SLOTS];
  __shared__ u32 dbuf[2048];
  __shared__ float wsum[4];
  const int t = threadIdx.x, lane = t & 63, wave = t >> 6;
  for (int s = t; s < S_SLOTS; s += 256) str[s] = strengths0[s];
  __syncthreads();
  for (int c = 0; c < N_ITEMS; c += 2048) {
    for (int k = t; k < 2048; k += 256) dbuf[k] = (u32)(decs[c + k] & 0xFFFFFFFFull);
    __syncthreads();
    if (t == 0) {
      for (int k = 0; k < 2048; k++) {
        const u32 dd = dbuf[k];
        const int slot = (int)(dd & 0x7FFFFFFFu);
        if (dd & 0x80000000u) str[slot] += 1.f; else str[slot] = 1.f;
      }
    }
    __syncthreads();
  }
  const int num = state[0];
  float* outs = out + (size_t)S_SLOTS * D_SEM;
  float lsum = 0.f;
  for (int s = t; s < S_SLOTS; s += 256) {
    const float v = str[s];
    outs[s] = v;
    if (s < num) lsum += v;
  }
#pragma unroll
  for (int o = 32; o; o >>= 1) lsum += __shfl_down(lsum, o, 64);
  if (lane == 0) wsum[wave] = lsum;
  __syncthreads();
  if (t == 0) {
    const float total = wsum[0] + wsum[1] + wsum[2] + wsum[3];
    float denom = (float)num;
    if (denom < 1.f) denom = 1.f;
    outs[S_SLOTS + 0] = (float)num;
    outs[S_SLOTS + 1] = (float)N_ITEMS;
    outs[S_SLOTS + 2] = (num > 0) ? (total / denom) : 0.f;
  }
}

// ---------------------------------------------------------------------------
extern "C" void kernel_launch(void* const* d_in, const int* in_sizes, int n_in,
                              void* d_out, int out_size, void* d_ws, size_t ws_size,
                              hipStream_t stream) {
  const float* states  = (const float*)d_in[0];
  const float* rewards = (const float*)d_in[1];
  const float* W       = (const float*)d_in[2];
  const float* bias    = (const float*)d_in[3];
  const float* traces0 = (const float*)d_in[4];
  const float* str0    = (const float*)d_in[5];
  float* out = (float*)d_out;   // traces live here (working + final)

  // ws layout (~24.5 MB): content chunk 16MB | Q 4MB | Gram 4MB | n_g | decs | state
  char* p = (char*)d_ws;
  float* cbuf = (float*)p;                 p += (size_t)CHUNK_ITEMS * D_SEM * 4;
  float* Q    = (float*)p;                 p += (size_t)B_ITEMS * S_SLOTS * 4;
  float* Gb   = (float*)p;                 p += (size_t)CHUNK_BLKS * B_ITEMS * B_ITEMS * 4;
  float* n_g  = (float*)p;                 p += (size_t)S_SLOTS * 4;
  u64*   decs = (u64*)p;                   p += (size_t)N_ITEMS * 8;
  int*   state = (int*)p;

  init_kernel<<<S_SLOTS, 256, 0, stream>>>(traces0, out, n_g, state);

  for (int c = 0; c < N_ITEMS / CHUNK_ITEMS; c++) {
    gemm_kernel<<<dim3(CHUNK_ITEMS / 64, D_SEM / 64), 256, 0, stream>>>(
        states + (size_t)c * CHUNK_ITEMS * D_STATE, W, bias, cbuf);
    gram_kernel<<<dim3(4, 4, CHUNK_BLKS), 256, 0, stream>>>(cbuf, Gb);
    for (int bb = 0; bb < CHUNK_BLKS; bb++) {
      const int b = c * CHUNK_BLKS + bb;
      const float* cblk = cbuf + (size_t)bb * B_ITEMS * D_SEM;
      const float* Gblk = Gb + (size_t)bb * B_ITEMS * B_ITEMS;
      pgemm_kernel<<<dim3(4, S_SLOTS / 64), 256, 0, stream>>>(cblk, out, n_g, Q, state);
      scan_kernel<<<1, 512, 0, stream>>>(Q, Gblk, rewards + (size_t)b * B_ITEMS,
                                         n_g, state, decs + (size_t)b * B_ITEMS);
      apply_kernel<<<B_ITEMS, 256, 0, stream>>>(cblk, decs + (size_t)b * B_ITEMS,
                                                out, n_g);
    }
  }
  finalize_kernel<<<1, 256, 0, stream>>>(str0, decs, state, out);
}